// Round 1
// baseline (102.633 us; speedup 1.0000x reference)
//
#include <hip/hip_runtime.h>
#include <hip/hip_bf16.h>
#include <math.h>

// Problem constants: B=64, D=64, C=128, H=64
#define CC 128
#define BB 64
#define DD 64
#define HH 64
#define NPAIRS 8128          // C*(C-1)/2
#define CHUNK 4
#define NBLK2 (NPAIRS / CHUNK)   // 2032

struct Slots { double j; double l; };

#define OFF(i) ((i)*127 - ((i)*((i)-1))/2)

// ---------------------------------------------------------------------------
// Kernel 1: A1[b,c,h] = sum_d x[b,d,c]*W1[d,h] + b1[h]
//           B2[b,c,h] = sum_d x[b,d,c]*W1[64+d,h]
// grid = 256 blocks (b = blk>>2, c-quarter = blk&3), 256 threads.
__global__ __launch_bounds__(256) void k1_tables(
    const float* __restrict__ x, const float* __restrict__ W1,
    const float* __restrict__ b1,
    float* __restrict__ A1, float* __restrict__ B2)
{
    __shared__ float xs[64][32];    // x[b][d][c-local]
    __shared__ float w1s[128][64];  // full W1
    int b  = blockIdx.x >> 2;
    int cq = blockIdx.x & 3;

    // stage W1 (8192 floats) as float4
    for (int idx = threadIdx.x; idx < 2048; idx += 256)
        ((float4*)w1s)[idx] = ((const float4*)W1)[idx];
    // stage x[b][:, cq*32 .. cq*32+31]
    for (int idx = threadIdx.x; idx < 2048; idx += 256) {
        int d = idx >> 5, cl = idx & 31;
        xs[d][cl] = x[((size_t)b * 64 + d) * 128 + cq * 32 + cl];
    }
    __syncthreads();

    int h  = threadIdx.x & 63;          // lane -> h (coalesced stores)
    int c0 = (threadIdx.x >> 6) * 8;    // wave -> c-local block of 8

    float accA[8] = {0,0,0,0,0,0,0,0};
    float accB[8] = {0,0,0,0,0,0,0,0};
    for (int d = 0; d < 64; ++d) {
        float wa = w1s[d][h];
        float wb = w1s[64 + d][h];
        float xv[8];
        *(float4*)&xv[0] = *(const float4*)&xs[d][c0];     // wave-uniform -> broadcast
        *(float4*)&xv[4] = *(const float4*)&xs[d][c0 + 4];
        #pragma unroll
        for (int k = 0; k < 8; ++k) {
            accA[k] = fmaf(xv[k], wa, accA[k]);
            accB[k] = fmaf(xv[k], wb, accB[k]);
        }
    }
    float bias = b1[h];
    #pragma unroll
    for (int k = 0; k < 8; ++k) {
        int c = cq * 32 + c0 + k;
        size_t o = ((size_t)b * CC + c) * HH + h;
        A1[o] = accA[k] + bias;   // fold b1 into A1
        B2[o] = accB[k];
    }
}

// ---------------------------------------------------------------------------
// Kernel 2: per-pair joint + lse. lane = batch. One wave per block,
// CHUNK consecutive triu pairs per block. Per-block double partial sums.
__global__ __launch_bounds__(64) void k2_pairs(
    const float* __restrict__ A1, const float* __restrict__ B2,
    const int* __restrict__ perm, const float* __restrict__ W2,
    Slots* __restrict__ slots)
{
    int lane = threadIdx.x;
    __shared__ int invp_s[64];
    invp_s[perm[lane]] = lane;
    __syncthreads();
    int ip = invp_s[lane];   // invperm[lane]

    const float4* __restrict__ W2v = (const float4*)W2;  // uniform -> SGPRs

    float4 a1r[16], a2r[16];     // A1[lane,i,:] and A1[invperm[lane],i,:]
    double jd = 0.0, ld = 0.0;

    int p0 = blockIdx.x * CHUNK;
    // decode p0 -> (i,j) in triu row-major order
    double tt = 127.5 - sqrt(127.5 * 127.5 - 2.0 * (double)p0);
    int i = (int)tt;
    if (i < 0) i = 0;
    if (i > 126) i = 126;
    while (i < 126 && OFF(i + 1) <= p0) ++i;
    while (i > 0 && OFF(i) > p0) --i;
    int j = i + 1 + (p0 - OFF(i));

    bool need_load = true;
    for (int k = 0; k < CHUNK; ++k) {
        if (need_load) {
            const float4* ar1 = (const float4*)(A1 + ((size_t)lane * CC + i) * HH);
            const float4* ar2 = (const float4*)(A1 + ((size_t)ip   * CC + i) * HH);
            #pragma unroll
            for (int q = 0; q < 16; ++q) { a1r[q] = ar1[q]; a2r[q] = ar2[q]; }
            need_load = false;
        }
        const float4* br = (const float4*)(B2 + ((size_t)lane * CC + j) * HH);
        float accJ = 0.f, accM = 0.f;
        #pragma unroll
        for (int q = 0; q < 16; ++q) {
            float4 bq = br[q];
            float4 w  = W2v[q];
            accJ = fmaf(fmaxf(a1r[q].x + bq.x, 0.f), w.x, accJ);
            accJ = fmaf(fmaxf(a1r[q].y + bq.y, 0.f), w.y, accJ);
            accJ = fmaf(fmaxf(a1r[q].z + bq.z, 0.f), w.z, accJ);
            accJ = fmaf(fmaxf(a1r[q].w + bq.w, 0.f), w.w, accJ);
            accM = fmaf(fmaxf(a2r[q].x + bq.x, 0.f), w.x, accM);
            accM = fmaf(fmaxf(a2r[q].y + bq.y, 0.f), w.y, accM);
            accM = fmaf(fmaxf(a2r[q].z + bq.z, 0.f), w.z, accM);
            accM = fmaf(fmaxf(a2r[q].w + bq.w, 0.f), w.w, accM);
        }
        // joint accumulation (per-lane, reduced at end)
        jd += (double)accJ;
        // lse over the 64 lanes (the marginal batch set)
        float m = accM;
        #pragma unroll
        for (int off = 32; off > 0; off >>= 1)
            m = fmaxf(m, __shfl_xor(m, off));
        float e = expf(accM - m);
        #pragma unroll
        for (int off = 32; off > 0; off >>= 1)
            e += __shfl_xor(e, off);
        if (lane == 0) ld += (double)(m + logf(e));

        ++j;
        if (j == CC) { ++i; j = i + 1; need_load = true; }
    }
    // wave-reduce joint partial
    #pragma unroll
    for (int off = 32; off > 0; off >>= 1)
        jd += __shfl_xor(jd, off);
    if (lane == 0) { slots[blockIdx.x].j = jd; slots[blockIdx.x].l = ld; }
}

// ---------------------------------------------------------------------------
// Kernel 3: reduce 2032 slot pairs, compute final scalar.
__global__ __launch_bounds__(256) void k3_final(
    const Slots* __restrict__ slots, float* __restrict__ out)
{
    __shared__ double sj[4], sl[4];
    double jd = 0.0, ld = 0.0;
    for (int s = threadIdx.x; s < NBLK2; s += 256) {
        jd += slots[s].j;
        ld += slots[s].l;
    }
    #pragma unroll
    for (int off = 32; off > 0; off >>= 1) {
        jd += __shfl_xor(jd, off);
        ld += __shfl_xor(ld, off);
    }
    int w = threadIdx.x >> 6;
    if ((threadIdx.x & 63) == 0) { sj[w] = jd; sl[w] = ld; }
    __syncthreads();
    if (threadIdx.x == 0) {
        jd = sj[0] + sj[1] + sj[2] + sj[3];
        ld = sl[0] + sl[1] + sl[2] + sl[3];
        // total_mi = (1/B)*sum_joint - sum_lse + P*log(B); out = -total_mi/P
        double total = jd / 64.0 - ld + 8128.0 * log(64.0);
        out[0] = (float)(-total / 8128.0);
    }
}

// ---------------------------------------------------------------------------
extern "C" void kernel_launch(void* const* d_in, const int* in_sizes, int n_in,
                              void* d_out, int out_size, void* d_ws, size_t ws_size,
                              hipStream_t stream)
{
    const float* x   = (const float*)d_in[0];
    const float* W1  = (const float*)d_in[1];
    const float* b1  = (const float*)d_in[2];
    const float* W2  = (const float*)d_in[3];
    // b2 (d_in[4]) cancels exactly in joint - lse; unused.
    const int*  perm = (const int*)d_in[5];

    char* ws = (char*)d_ws;
    Slots* slots = (Slots*)ws;                         // 2032 * 16 B = 32.5 KB
    float* A1 = (float*)(ws + 40960);                  // 2 MB
    float* B2 = A1 + (size_t)BB * CC * HH;             // 2 MB

    k1_tables<<<256, 256, 0, stream>>>(x, W1, b1, A1, B2);
    k2_pairs<<<NBLK2, 64, 0, stream>>>(A1, B2, perm, W2, slots);
    k3_final<<<1, 256, 0, stream>>>(slots, (float*)d_out);
}